// Round 10
// baseline (7354.688 us; speedup 1.0000x reference)
//
#include <hip/hip_runtime.h>
#include <math.h>

// np-faithful f32 helpers -----------------------------------------------------
__device__ __forceinline__ float np_exp(float x) { return (float)exp((double)x); }

__device__ __forceinline__ float glif_step(float xn, float& ii, float& vv, float& ss, float& aa) {
  ii = __fadd_rn(__fmul_rn(0.5f, ii), xn);
  float vr = __fmul_rn(__fmul_rn(0.75f, vv), __fsub_rn(1.0f, ss));
  vv = __fadd_rn(vr, ii);
  float th = __fadd_rn(1.0f, __fmul_rn(0.1f, aa));
  float u = __fsub_rn(vv, th);
  float ns = u > 0.0f ? 1.0f : 0.0f;
  aa = __fadd_rn(__fmul_rn(0.9f, aa), ns);
  ss = ns;
  return ns;
}

__device__ __forceinline__ float gn_apply(float x, float m, float r, float w, float b) {
  return __fadd_rn(__fmul_rn(__fmul_rn(__fsub_rn(x, m), r), w), b);
}

// ============ stats kernels: DO NOT TOUCH (reduction order pinned, verified absmax=0) ============
__global__ __launch_bounds__(64) void f_stats_wave(const float* __restrict__ xsrc,
                                                   float2* __restrict__ mr, int n)
{
  int blk = blockIdx.x;
  int lane = threadIdx.x;
  const float* base = xsrc + (size_t)blk * n;
  double sum = 0.0;
  for (int i = lane; i < n; i += 64) sum += (double)base[i];
  for (int off = 32; off > 0; off >>= 1) sum += __shfl_down(sum, off, 64);
  sum = __shfl(sum, 0, 64);
  float m = (float)(sum / (double)n);
  double sq = 0.0;
  for (int i = lane; i < n; i += 64) {
    float d = __fsub_rn(base[i], m);
    float s2 = __fmul_rn(d, d);
    sq += (double)s2;
  }
  for (int off = 32; off > 0; off >>= 1) sq += __shfl_down(sq, off, 64);
  if (lane == 0) {
    float var = (float)(sq / (double)n);
    float r = __fdiv_rn(1.0f, __fsqrt_rn(__fadd_rn(var, 1e-5f)));
    mr[blk] = make_float2(m, r);
  }
}

__global__ __launch_bounds__(256) void f_stats_serial(const float* __restrict__ xsrc,
                                                      float2* __restrict__ mr, int total)
{
  int gid = blockIdx.x * 256 + threadIdx.x;
  if (gid >= total) return;
  const float* base = xsrc + (size_t)gid * 72;
  double sum = 0.0;
  for (int j = 0; j < 72; j++) sum += (double)base[j];
  float m = (float)(sum / 72.0);
  double sq = 0.0;
  for (int j = 0; j < 72; j++) {
    float d = __fsub_rn(base[j], m);
    float s2 = __fmul_rn(d, d);
    sq += (double)s2;
  }
  float var = (float)(sq / 72.0);
  mr[gid] = make_float2(m, __fdiv_rn(1.0f, __fsqrt_rn(__fadd_rn(var, 1e-5f))));
}

// ============ K1: conv0 (r8-verbatim, gid per output); chain (ky,kx) asc mul+add ============
__global__ __launch_bounds__(256) void f_conv0(
    const float* __restrict__ x, const float* __restrict__ w0, const float* __restrict__ b0,
    float* __restrict__ c0)
{
  int gid = blockIdx.x * 256 + threadIdx.x;
  if (gid >= 7372800) return;
  int p = gid % 900;
  int c = (gid / 900) % 64;
  int b = gid / 57600;
  int oy = p / 30, ox = p % 30;
  float acc = 0.0f;
  for (int ky = 0; ky < 7; ky++)
    for (int kx = 0; kx < 7; kx++)
      acc = __fadd_rn(acc, __fmul_rn(w0[c * 49 + ky * 7 + kx],
                                     x[b * 1296 + (oy + ky) * 36 + (ox + kx)]));
  c0[gid] = __fadd_rn(acc, b0[c]);
}

// ============ K3: GN0 apply + GLIF0 -> h0 u8 ============
__global__ __launch_bounds__(256) void f_glif0(
    const float* __restrict__ c0, const float2* __restrict__ mr0,
    const float* __restrict__ gnw, const float* __restrict__ gnb, unsigned char* __restrict__ h0)
{
  int gid = blockIdx.x * 256 + threadIdx.x;
  if (gid >= 7372800) return;
  int c = (gid / 900) % 64;
  int b = gid / 57600;
  float2 mrv = mr0[b * 8 + (c >> 3)];
  float xn = gn_apply(c0[gid], mrv.x, mrv.y, gnw[c], gnb[c]);
  float ii = 0.f, vv = 0.f, ss = 0.f, aa = 0.f;
  for (int t = 0; t < 8; t++) {
    float ns = glif_step(xn, ii, vv, ss, aa);
    h0[(size_t)t * 7372800 + gid] = (unsigned char)ns;
  }
}

// ============ K4: conv1 LDS-staged (r8 compute, + occupancy hint) ============
__global__ __launch_bounds__(256, 5) void f_conv1(
    const unsigned char* __restrict__ h0, const float* __restrict__ w1,
    const float* __restrict__ b1, float* __restrict__ y1)
{
  int tb = blockIdx.x;
  int tid = threadIdx.x;
  __shared__ float sp[7200];   // 8 ic x 900
  int ot = tid >> 4;
  int pg = tid & 15;
  int och0 = ot * 4;
  int oy0 = (pg >> 2) * 3;
  int ox0 = (pg & 3) * 3;
  float acc[4][9];
#pragma unroll
  for (int j = 0; j < 4; j++)
#pragma unroll
    for (int p = 0; p < 9; p++) acc[j][p] = 0.0f;

  for (int icc = 0; icc < 8; icc++) {
    int ic0 = icc * 8;
    __syncthreads();
    {
      const unsigned int* src = (const unsigned int*)(h0 + (size_t)tb * 57600 + (size_t)ic0 * 900);
      float4* dst = (float4*)sp;
      for (int i = tid; i < 1800; i += 256) {
        unsigned int u = src[i];
        dst[i] = make_float4((float)(u & 0xFF), (float)((u >> 8) & 0xFF),
                             (float)((u >> 16) & 0xFF), (float)((u >> 24) & 0xFF));
      }
    }
    __syncthreads();
    for (int ic = 0; ic < 8; ic++) {
      const float* wq = w1 + ((size_t)och0 * 64 + ic0 + ic) * 49;
      const float* spc = sp + ic * 900;
#pragma unroll
      for (int ky = 0; ky < 7; ky++) {
        float rowv[3][12];
#pragma unroll
        for (int r = 0; r < 3; r++) {
          const float* rp = spc + (2 * (oy0 + r) + ky) * 30 + 2 * ox0;
#pragma unroll
          for (int d = 0; d < 6; d++) {
            float2 t2 = *(const float2*)(rp + 2 * d);
            rowv[r][2 * d] = t2.x; rowv[r][2 * d + 1] = t2.y;
          }
        }
#pragma unroll
        for (int kx = 0; kx < 7; kx++) {
          float wv[4];
#pragma unroll
          for (int j = 0; j < 4; j++) wv[j] = wq[j * 3136 + ky * 7 + kx];
#pragma unroll
          for (int r = 0; r < 3; r++)
#pragma unroll
            for (int c = 0; c < 3; c++) {
              float sv = rowv[r][kx + 2 * c];
#pragma unroll
              for (int j = 0; j < 4; j++)
                acc[j][r * 3 + c] = __fadd_rn(acc[j][r * 3 + c], __fmul_rn(wv[j], sv));
            }
        }
      }
    }
  }
#pragma unroll
  for (int j = 0; j < 4; j++) {
    int och = och0 + j;
    float bb = b1[och];
#pragma unroll
    for (int r = 0; r < 3; r++)
#pragma unroll
      for (int c = 0; c < 3; c++)
        y1[((size_t)tb * 64 + och) * 144 + (oy0 + r) * 12 + (ox0 + c)] =
            __fadd_rn(acc[j][r * 3 + c], bb);
  }
}

// ============ K6: GN1 apply + GLIF1 -> h1 u8 ============
__global__ __launch_bounds__(256) void f_glif1(
    const float* __restrict__ y1, const float2* __restrict__ mr1,
    const float* __restrict__ gnw, const float* __restrict__ gnb, unsigned char* __restrict__ h1)
{
  int gid = blockIdx.x * 256 + threadIdx.x;
  if (gid >= 1179648) return;
  int b = gid / 9216;
  int r = gid % 9216;
  int ch = r / 144;
  int g = ch >> 3;
  float gw = gnw[ch], gb = gnb[ch];
  float ii = 0.f, vv = 0.f, ss = 0.f, aa = 0.f;
  for (int t = 0; t < 8; t++) {
    int tb = t * 128 + b;
    float2 mrv = mr1[tb * 8 + g];
    float xn = gn_apply(y1[(size_t)tb * 9216 + r], mrv.x, mrv.y, gw, gb);
    float ns = glif_step(xn, ii, vv, ss, aa);
    h1[(size_t)tb * 9216 + r] = (unsigned char)ns;
  }
}

// ============ K7: conv2 (r8-verbatim, 576 threads, one output/thread) ============
__global__ __launch_bounds__(576) void f_conv2(
    const unsigned char* __restrict__ h1, const float* __restrict__ w2,
    const float* __restrict__ b2, float* __restrict__ y2)
{
  int tb = blockIdx.x;
  int tid = threadIdx.x;
  __shared__ float sp[9216];   // 64 ic x 144
  {
    const unsigned int* src = (const unsigned int*)(h1 + (size_t)tb * 9216);
    float4* dst = (float4*)sp;
    for (int i = tid; i < 2304; i += 576) {
      unsigned int u = src[i];
      dst[i] = make_float4((float)(u & 0xFF), (float)((u >> 8) & 0xFF),
                           (float)((u >> 16) & 0xFF), (float)((u >> 24) & 0xFF));
    }
  }
  __syncthreads();
  int oc = tid / 9;
  int p = tid % 9;
  int oy = p / 3, ox = p % 3;
  float acc = 0.0f;
  const float* wb = w2 + (size_t)oc * 64 * 49;
  for (int ic = 0; ic < 64; ic++) {
    const float* spc = sp + ic * 144;
    const float* wq = wb + ic * 49;
#pragma unroll
    for (int ky = 0; ky < 7; ky++) {
      const float* rp = spc + (2 * oy + ky) * 12 + 2 * ox;
      float rowv[8];
#pragma unroll
      for (int d = 0; d < 4; d++) {
        float2 t2 = *(const float2*)(rp + 2 * d);
        rowv[2 * d] = t2.x; rowv[2 * d + 1] = t2.y;
      }
#pragma unroll
      for (int kx = 0; kx < 7; kx++)
        acc = __fadd_rn(acc, __fmul_rn(wq[ky * 7 + kx], rowv[kx]));
    }
  }
  y2[(size_t)tb * 576 + oc * 9 + p] = __fadd_rn(acc, b2[oc]);
}

// ============ K9: GN2 apply + GLIF2 -> h2 f32 spikes [tb,576] ============
__global__ __launch_bounds__(256) void f_glif2(
    const float* __restrict__ y2, const float2* __restrict__ mr2,
    const float* __restrict__ gnw, const float* __restrict__ gnb, float* __restrict__ h2)
{
  int gid = blockIdx.x * 256 + threadIdx.x;
  if (gid >= 73728) return;
  int b = gid / 576;
  int e = gid % 576;
  int c = e / 9;
  int g = e / 72;
  float gw = gnw[c], gb = gnb[c];
  float ii = 0.f, vv = 0.f, ss = 0.f, aa = 0.f;
  for (int t = 0; t < 8; t++) {
    int tb = t * 128 + b;
    float2 mrv = mr2[tb * 8 + g];
    float xn = gn_apply(y2[(size_t)tb * 576 + e], mrv.x, mrv.y, gw, gb);
    float ns = glif_step(xn, ii, vv, ss, aa);
    h2[(size_t)tb * 576 + e] = ns;
  }
}

// ============ K10: fused MHA (block per tb); per-output chains == r8's 4 separate kernels ============
__global__ __launch_bounds__(256) void f_mha(
    const float* __restrict__ h2, const float* __restrict__ wi, const float* __restrict__ bi,
    const float* __restrict__ wo, const float* __restrict__ bo, float* __restrict__ feat)
{
  int tb = blockIdx.x;
  int tid = threadIdx.x;
  __shared__ float tokl[576];    // [s][64]
  __shared__ float qkvl[1728];   // [s][192]
  __shared__ float attl[324];    // [h][qi][kj]
  __shared__ float obufl[576];   // [s][64]
  for (int i = tid; i < 576; i += 256) {
    int c = i / 9, s = i % 9;
    tokl[s * 64 + c] = h2[(size_t)tb * 576 + i];
  }
  __syncthreads();
  // qkv: fma chain over c ascending, bias after (== f_qkv)
  for (int o = tid; o < 1728; o += 256) {
    int s = o / 192, j = o % 192;
    const float* wr = wi + j * 64;
    const float* tr = tokl + s * 64;
    float acc = 0.0f;
    for (int c = 0; c < 64; c++) acc = __fmaf_rn(tr[c], wr[c], acc);
    qkvl[o] = __fadd_rn(acc, bi[j]);
  }
  __syncthreads();
  // logits (mul+add over d) + softmax (np tree) (== f_att)
  if (tid < 36) {
    int qi = tid % 9;
    int h = tid / 9;
    float lg[9];
    for (int kj = 0; kj < 9; kj++) {
      float acc = 0.0f;
      for (int d = 0; d < 16; d++)
        acc = __fadd_rn(acc, __fmul_rn(qkvl[qi * 192 + h * 16 + d],
                                       qkvl[kj * 192 + 64 + h * 16 + d]));
      lg[kj] = __fmul_rn(acc, 0.25f);
    }
    float mx = lg[0];
    for (int kj = 1; kj < 9; kj++) mx = fmaxf(mx, lg[kj]);
    float ev[9];
    for (int kj = 0; kj < 9; kj++) ev[kj] = np_exp(__fsub_rn(lg[kj], mx));
    float s01 = __fadd_rn(ev[0], ev[1]), s23 = __fadd_rn(ev[2], ev[3]);
    float s45 = __fadd_rn(ev[4], ev[5]), s67 = __fadd_rn(ev[6], ev[7]);
    float sum = __fadd_rn(__fadd_rn(s01, s23), __fadd_rn(s45, s67));
    sum = __fadd_rn(sum, ev[8]);
    for (int kj = 0; kj < 9; kj++)
      attl[h * 81 + qi * 9 + kj] = __fdiv_rn(ev[kj], sum);
  }
  __syncthreads();
  // att @ V: mul+add over j ascending (== f_attv)
  for (int o = tid; o < 576; o += 256) {
    int f = o % 64;
    int s = o / 64;
    int h = f >> 4;
    float acc = 0.0f;
    for (int j = 0; j < 9; j++)
      acc = __fadd_rn(acc, __fmul_rn(attl[h * 81 + s * 9 + j], qkvl[j * 192 + 128 + f]));
    obufl[s * 64 + f] = acc;
  }
  __syncthreads();
  // out-proj: fma chain over f ascending, bias after (== f_proj)
  for (int o = tid; o < 576; o += 256) {
    int s = o % 9;
    int e = o / 9;
    float acc = 0.0f;
    for (int f = 0; f < 64; f++)
      acc = __fmaf_rn(obufl[s * 64 + f], wo[e * 64 + f], acc);
    feat[(size_t)tb * 576 + e * 9 + s] = __fadd_rn(acc, bo[e]);
  }
}

// ============ K11: FC tiled GEMM; chain k=0..575 ascending fma, bias after ============
__global__ __launch_bounds__(256) void f_fc(
    const float* __restrict__ feat, const float* __restrict__ fw, const float* __restrict__ fb,
    float* __restrict__ yfc)
{
  int mb = blockIdx.x;
  int nb = blockIdx.y;
  int tid = threadIdx.x;
  __shared__ float At[32 * 68];
  __shared__ float Bt[32 * 68];
  int tn = tid >> 4, tm = tid & 15;
  int n4 = tn * 4, m4 = tm * 4;
  float acc[4][4];
#pragma unroll
  for (int i = 0; i < 4; i++)
#pragma unroll
    for (int j = 0; j < 4; j++) acc[i][j] = 0.0f;
  for (int kc = 0; kc < 18; kc++) {
    int k0 = kc * 32;
    __syncthreads();
    for (int l = tid; l < 2048; l += 256) {
      int n = l >> 5, k = l & 31;
      At[k * 68 + n] = feat[(size_t)(nb * 64 + n) * 576 + k0 + k];
      Bt[k * 68 + n] = fw[(size_t)(mb * 64 + n) * 576 + k0 + k];
    }
    __syncthreads();
#pragma unroll 8
    for (int k = 0; k < 32; k++) {
      float av[4], bv[4];
#pragma unroll
      for (int i = 0; i < 4; i++) av[i] = At[k * 68 + n4 + i];
#pragma unroll
      for (int j = 0; j < 4; j++) bv[j] = Bt[k * 68 + m4 + j];
#pragma unroll
      for (int i = 0; i < 4; i++)
#pragma unroll
        for (int j = 0; j < 4; j++) acc[i][j] = __fmaf_rn(av[i], bv[j], acc[i][j]);
    }
  }
#pragma unroll
  for (int i = 0; i < 4; i++) {
    int n = nb * 64 + n4 + i;
    int m = mb * 64 + m4;
#pragma unroll
    for (int j = 0; j < 4; j++)
      yfc[(size_t)n * 2304 + m + j] = __fadd_rn(acc[i][j], fb[m + j]);
  }
}

// ============ K13: GNfc apply + GLIFfc -> hf u8 [t][b][2304] ============
__global__ __launch_bounds__(256) void f_gliffc(
    const float* __restrict__ yfc, const float2* __restrict__ mrfc,
    const float* __restrict__ gnw, const float* __restrict__ gnb, unsigned char* __restrict__ hf)
{
  int gid = blockIdx.x * 256 + threadIdx.x;
  if (gid >= 294912) return;
  int c = gid % 2304;
  int b = gid / 2304;
  int g = c / 72;
  float gw = gnw[c], gb = gnb[c];
  float ii = 0.f, vv = 0.f, ss = 0.f, aa = 0.f;
  for (int t = 0; t < 8; t++) {
    int tb = t * 128 + b;
    float2 mrv = mrfc[tb * 32 + g];
    float xn = gn_apply(yfc[(size_t)tb * 2304 + c], mrv.x, mrv.y, gw, gb);
    float ns = glif_step(xn, ii, vv, ss, aa);
    hf[(size_t)t * 294912 + (size_t)b * 2304 + c] = (unsigned char)ns;
  }
}

// ============ K14a: head per (b,nc,t): fma chain c ascending (uint-packed spike loads) ============
__global__ __launch_bounds__(256) void f_head_t(
    const unsigned char* __restrict__ hf, const float* __restrict__ head_w,
    const float* __restrict__ head_b, const float* __restrict__ wt, float* __restrict__ hbuf)
{
  int gid = blockIdx.x * 256 + threadIdx.x;
  if (gid >= 9216) return;
  int t = gid % 8;
  int nc = (gid / 8) % 9;
  int b = gid / 72;
  const float* wr = head_w + (size_t)nc * 2304;
  const unsigned int* hr = (const unsigned int*)(hf + (size_t)t * 294912 + (size_t)b * 2304);
  float acc = 0.0f;
  for (int c4 = 0; c4 < 576; c4++) {
    unsigned int u = hr[c4];
    int c = c4 * 4;
    acc = __fmaf_rn((float)(u & 0xFF), wr[c], acc);
    acc = __fmaf_rn((float)((u >> 8) & 0xFF), wr[c + 1], acc);
    acc = __fmaf_rn((float)((u >> 16) & 0xFF), wr[c + 2], acc);
    acc = __fmaf_rn((float)((u >> 24) & 0xFF), wr[c + 3], acc);
  }
  float ot = __fadd_rn(acc, head_b[nc]);
  hbuf[gid] = __fmul_rn(ot, wt[t]);
}

// ============ K14b: sum over t ascending ============
__global__ __launch_bounds__(256) void f_head_sum(
    const float* __restrict__ hbuf, float* __restrict__ out)
{
  int gid = blockIdx.x * 256 + threadIdx.x;
  if (gid >= 1152) return;
  float outv = 0.0f;
  for (int t = 0; t < 8; t++) outv = __fadd_rn(outv, hbuf[gid * 8 + t]);
  out[gid] = outv;
}

// ===================== launch =====================
extern "C" void kernel_launch(void* const* d_in, const int* in_sizes, int n_in,
                              void* d_out, int out_size, void* d_ws, size_t ws_size,
                              hipStream_t stream) {
  (void)in_sizes; (void)n_in; (void)out_size; (void)ws_size;
  const float* x       = (const float*)d_in[0];
  const float* conv0_w = (const float*)d_in[1];
  const float* conv0_b = (const float*)d_in[2];
  const float* gn0_w   = (const float*)d_in[3];
  const float* gn0_b   = (const float*)d_in[4];
  const float* conv1_w = (const float*)d_in[5];
  const float* conv1_b = (const float*)d_in[6];
  const float* gn1_w   = (const float*)d_in[7];
  const float* gn1_b   = (const float*)d_in[8];
  const float* conv2_w = (const float*)d_in[9];
  const float* conv2_b = (const float*)d_in[10];
  const float* gn2_w   = (const float*)d_in[11];
  const float* gn2_b   = (const float*)d_in[12];
  const float* wi      = (const float*)d_in[13];
  const float* bi      = (const float*)d_in[14];
  const float* wo      = (const float*)d_in[15];
  const float* bo      = (const float*)d_in[16];
  const float* fc_w    = (const float*)d_in[17];
  const float* fc_b    = (const float*)d_in[18];
  const float* gnfc_w  = (const float*)d_in[19];
  const float* gnfc_b  = (const float*)d_in[20];
  const float* head_w  = (const float*)d_in[21];
  const float* head_b  = (const float*)d_in[22];
  const float* w_t     = (const float*)d_in[23];

  // workspace layout: identical to the r8 PASSING build
  char* ws = (char*)d_ws;
  unsigned char* h0   = (unsigned char*)(ws);               // [0, 58982400)
  float*         c0   = (float*)(ws + 58982400);            // 29491200 B -> 88473600
  float*         y1   = (float*)(ws + 88473600);            // 37748736 B -> 126222336
  unsigned char* h1   = (unsigned char*)(ws + 126222336);   //  9437184 B -> 135659520
  float*         y2   = (float*)(ws + 135659520);           //  2359296 B -> 138018816
  float*         h2   = (float*)(ws + 138018816);           //  2359296 B -> 140378112
  // late-phase buffers alias c0's region (c0 dead after f_glif0)
  float*         feat = (float*)(ws + 69746688);            //  2359296 B -> 72105984
  float*         yfc  = (float*)(ws + 72105984);            //  9437184 B -> 81543168
  unsigned char* hf   = (unsigned char*)(ws + 81543168);    //  2359296 B -> 83902464 (< 88473600 OK)
  float2*        mr0  = (float2*)(ws + 151142400);          //     8192 B
  float2*        mr1  = (float2*)(ws + 151150592);          //    65536 B
  float2*        mr2  = (float2*)(ws + 151216128);          //    65536 B
  float2*        mrfc = (float2*)(ws + 151281664);          //   262144 B -> 151543808
  float*         hbuf = (float*)(ws + 151543808);           //    36864 B -> 151580672

  f_conv0<<<28800, 256, 0, stream>>>(x, conv0_w, conv0_b, c0);
  f_stats_wave<<<1024, 64, 0, stream>>>(c0, mr0, 7200);
  f_glif0<<<28800, 256, 0, stream>>>(c0, mr0, gn0_w, gn0_b, h0);
  f_conv1<<<1024, 256, 0, stream>>>(h0, conv1_w, conv1_b, y1);
  f_stats_wave<<<8192, 64, 0, stream>>>(y1, mr1, 1152);
  f_glif1<<<4608, 256, 0, stream>>>(y1, mr1, gn1_w, gn1_b, h1);
  f_conv2<<<1024, 576, 0, stream>>>(h1, conv2_w, conv2_b, y2);
  f_stats_serial<<<32, 256, 0, stream>>>(y2, mr2, 8192);
  f_glif2<<<288, 256, 0, stream>>>(y2, mr2, gn2_w, gn2_b, h2);
  f_mha<<<1024, 256, 0, stream>>>(h2, wi, bi, wo, bo, feat);
  dim3 gfc(36, 16);
  f_fc<<<gfc, 256, 0, stream>>>(feat, fc_w, fc_b, yfc);
  f_stats_serial<<<128, 256, 0, stream>>>(yfc, mrfc, 32768);
  f_gliffc<<<1152, 256, 0, stream>>>(yfc, mrfc, gnfc_w, gnfc_b, hf);
  f_head_t<<<36, 256, 0, stream>>>(hf, head_w, head_b, w_t, hbuf);
  f_head_sum<<<5, 256, 0, stream>>>(hbuf, (float*)d_out);
}

// Round 11
// 1689.314 us; speedup vs baseline: 4.3537x; 4.3537x over previous
//
#include <hip/hip_runtime.h>
#include <math.h>

// np-faithful f32 helpers -----------------------------------------------------
__device__ __forceinline__ float np_exp(float x) { return (float)exp((double)x); }

__device__ __forceinline__ float glif_step(float xn, float& ii, float& vv, float& ss, float& aa) {
  ii = __fadd_rn(__fmul_rn(0.5f, ii), xn);
  float vr = __fmul_rn(__fmul_rn(0.75f, vv), __fsub_rn(1.0f, ss));
  vv = __fadd_rn(vr, ii);
  float th = __fadd_rn(1.0f, __fmul_rn(0.1f, aa));
  float u = __fsub_rn(vv, th);
  float ns = u > 0.0f ? 1.0f : 0.0f;
  aa = __fadd_rn(__fmul_rn(0.9f, aa), ns);
  ss = ns;
  return ns;
}

__device__ __forceinline__ float gn_apply(float x, float m, float r, float w, float b) {
  return __fadd_rn(__fmul_rn(__fmul_rn(__fsub_rn(x, m), r), w), b);
}

// ============ stats kernels: DO NOT TOUCH (reduction order pinned, verified absmax=0) ============
__global__ __launch_bounds__(64) void f_stats_wave(const float* __restrict__ xsrc,
                                                   float2* __restrict__ mr, int n)
{
  int blk = blockIdx.x;
  int lane = threadIdx.x;
  const float* base = xsrc + (size_t)blk * n;
  double sum = 0.0;
  for (int i = lane; i < n; i += 64) sum += (double)base[i];
  for (int off = 32; off > 0; off >>= 1) sum += __shfl_down(sum, off, 64);
  sum = __shfl(sum, 0, 64);
  float m = (float)(sum / (double)n);
  double sq = 0.0;
  for (int i = lane; i < n; i += 64) {
    float d = __fsub_rn(base[i], m);
    float s2 = __fmul_rn(d, d);
    sq += (double)s2;
  }
  for (int off = 32; off > 0; off >>= 1) sq += __shfl_down(sq, off, 64);
  if (lane == 0) {
    float var = (float)(sq / (double)n);
    float r = __fdiv_rn(1.0f, __fsqrt_rn(__fadd_rn(var, 1e-5f)));
    mr[blk] = make_float2(m, r);
  }
}

__global__ __launch_bounds__(256) void f_stats_serial(const float* __restrict__ xsrc,
                                                      float2* __restrict__ mr, int total)
{
  int gid = blockIdx.x * 256 + threadIdx.x;
  if (gid >= total) return;
  const float* base = xsrc + (size_t)gid * 72;
  double sum = 0.0;
  for (int j = 0; j < 72; j++) sum += (double)base[j];
  float m = (float)(sum / 72.0);
  double sq = 0.0;
  for (int j = 0; j < 72; j++) {
    float d = __fsub_rn(base[j], m);
    float s2 = __fmul_rn(d, d);
    sq += (double)s2;
  }
  float var = (float)(sq / 72.0);
  mr[gid] = make_float2(m, __fdiv_rn(1.0f, __fsqrt_rn(__fadd_rn(var, 1e-5f))));
}

// ============ K1: conv0 (r8-verbatim, gid per output); chain (ky,kx) asc mul+add ============
__global__ __launch_bounds__(256) void f_conv0(
    const float* __restrict__ x, const float* __restrict__ w0, const float* __restrict__ b0,
    float* __restrict__ c0)
{
  int gid = blockIdx.x * 256 + threadIdx.x;
  if (gid >= 7372800) return;
  int p = gid % 900;
  int c = (gid / 900) % 64;
  int b = gid / 57600;
  int oy = p / 30, ox = p % 30;
  float acc = 0.0f;
  for (int ky = 0; ky < 7; ky++)
    for (int kx = 0; kx < 7; kx++)
      acc = __fadd_rn(acc, __fmul_rn(w0[c * 49 + ky * 7 + kx],
                                     x[b * 1296 + (oy + ky) * 36 + (ox + kx)]));
  c0[gid] = __fadd_rn(acc, b0[c]);
}

// ============ K3: GN0 apply + GLIF0 -> h0 u8 ============
__global__ __launch_bounds__(256) void f_glif0(
    const float* __restrict__ c0, const float2* __restrict__ mr0,
    const float* __restrict__ gnw, const float* __restrict__ gnb, unsigned char* __restrict__ h0)
{
  int gid = blockIdx.x * 256 + threadIdx.x;
  if (gid >= 7372800) return;
  int c = (gid / 900) % 64;
  int b = gid / 57600;
  float2 mrv = mr0[b * 8 + (c >> 3)];
  float xn = gn_apply(c0[gid], mrv.x, mrv.y, gnw[c], gnb[c]);
  float ii = 0.f, vv = 0.f, ss = 0.f, aa = 0.f;
  for (int t = 0; t < 8; t++) {
    float ns = glif_step(xn, ii, vv, ss, aa);
    h0[(size_t)t * 7372800 + gid] = (unsigned char)ns;
  }
}

// ============ K4: conv1 LDS-staged — r8-EXACT (no extra launch_bounds; VGPR 104, no spill) ============
__global__ __launch_bounds__(256) void f_conv1(
    const unsigned char* __restrict__ h0, const float* __restrict__ w1,
    const float* __restrict__ b1, float* __restrict__ y1)
{
  int tb = blockIdx.x;
  int tid = threadIdx.x;
  __shared__ float sp[7200];   // 8 ic x 900
  int ot = tid >> 4;
  int pg = tid & 15;
  int och0 = ot * 4;
  int oy0 = (pg >> 2) * 3;
  int ox0 = (pg & 3) * 3;
  float acc[4][9];
#pragma unroll
  for (int j = 0; j < 4; j++)
#pragma unroll
    for (int p = 0; p < 9; p++) acc[j][p] = 0.0f;

  for (int icc = 0; icc < 8; icc++) {
    int ic0 = icc * 8;
    __syncthreads();
    {
      const unsigned int* src = (const unsigned int*)(h0 + (size_t)tb * 57600 + (size_t)ic0 * 900);
      float4* dst = (float4*)sp;
      for (int i = tid; i < 1800; i += 256) {
        unsigned int u = src[i];
        dst[i] = make_float4((float)(u & 0xFF), (float)((u >> 8) & 0xFF),
                             (float)((u >> 16) & 0xFF), (float)((u >> 24) & 0xFF));
      }
    }
    __syncthreads();
    for (int ic = 0; ic < 8; ic++) {
      const float* wq = w1 + ((size_t)och0 * 64 + ic0 + ic) * 49;
      const float* spc = sp + ic * 900;
#pragma unroll
      for (int ky = 0; ky < 7; ky++) {
        float rowv[3][12];
#pragma unroll
        for (int r = 0; r < 3; r++) {
          const float* rp = spc + (2 * (oy0 + r) + ky) * 30 + 2 * ox0;
#pragma unroll
          for (int d = 0; d < 6; d++) {
            float2 t2 = *(const float2*)(rp + 2 * d);
            rowv[r][2 * d] = t2.x; rowv[r][2 * d + 1] = t2.y;
          }
        }
#pragma unroll
        for (int kx = 0; kx < 7; kx++) {
          float wv[4];
#pragma unroll
          for (int j = 0; j < 4; j++) wv[j] = wq[j * 3136 + ky * 7 + kx];
#pragma unroll
          for (int r = 0; r < 3; r++)
#pragma unroll
            for (int c = 0; c < 3; c++) {
              float sv = rowv[r][kx + 2 * c];
#pragma unroll
              for (int j = 0; j < 4; j++)
                acc[j][r * 3 + c] = __fadd_rn(acc[j][r * 3 + c], __fmul_rn(wv[j], sv));
            }
        }
      }
    }
  }
#pragma unroll
  for (int j = 0; j < 4; j++) {
    int och = och0 + j;
    float bb = b1[och];
#pragma unroll
    for (int r = 0; r < 3; r++)
#pragma unroll
      for (int c = 0; c < 3; c++)
        y1[((size_t)tb * 64 + och) * 144 + (oy0 + r) * 12 + (ox0 + c)] =
            __fadd_rn(acc[j][r * 3 + c], bb);
  }
}

// ============ K6: GN1 apply + GLIF1 -> h1 u8 ============
__global__ __launch_bounds__(256) void f_glif1(
    const float* __restrict__ y1, const float2* __restrict__ mr1,
    const float* __restrict__ gnw, const float* __restrict__ gnb, unsigned char* __restrict__ h1)
{
  int gid = blockIdx.x * 256 + threadIdx.x;
  if (gid >= 1179648) return;
  int b = gid / 9216;
  int r = gid % 9216;
  int ch = r / 144;
  int g = ch >> 3;
  float gw = gnw[ch], gb = gnb[ch];
  float ii = 0.f, vv = 0.f, ss = 0.f, aa = 0.f;
  for (int t = 0; t < 8; t++) {
    int tb = t * 128 + b;
    float2 mrv = mr1[tb * 8 + g];
    float xn = gn_apply(y1[(size_t)tb * 9216 + r], mrv.x, mrv.y, gw, gb);
    float ns = glif_step(xn, ii, vv, ss, aa);
    h1[(size_t)tb * 9216 + r] = (unsigned char)ns;
  }
}

// ============ K7: conv2 (r8-verbatim, 576 threads, one output/thread) ============
__global__ __launch_bounds__(576) void f_conv2(
    const unsigned char* __restrict__ h1, const float* __restrict__ w2,
    const float* __restrict__ b2, float* __restrict__ y2)
{
  int tb = blockIdx.x;
  int tid = threadIdx.x;
  __shared__ float sp[9216];   // 64 ic x 144
  {
    const unsigned int* src = (const unsigned int*)(h1 + (size_t)tb * 9216);
    float4* dst = (float4*)sp;
    for (int i = tid; i < 2304; i += 576) {
      unsigned int u = src[i];
      dst[i] = make_float4((float)(u & 0xFF), (float)((u >> 8) & 0xFF),
                           (float)((u >> 16) & 0xFF), (float)((u >> 24) & 0xFF));
    }
  }
  __syncthreads();
  int oc = tid / 9;
  int p = tid % 9;
  int oy = p / 3, ox = p % 3;
  float acc = 0.0f;
  const float* wb = w2 + (size_t)oc * 64 * 49;
  for (int ic = 0; ic < 64; ic++) {
    const float* spc = sp + ic * 144;
    const float* wq = wb + ic * 49;
#pragma unroll
    for (int ky = 0; ky < 7; ky++) {
      const float* rp = spc + (2 * oy + ky) * 12 + 2 * ox;
      float rowv[8];
#pragma unroll
      for (int d = 0; d < 4; d++) {
        float2 t2 = *(const float2*)(rp + 2 * d);
        rowv[2 * d] = t2.x; rowv[2 * d + 1] = t2.y;
      }
#pragma unroll
      for (int kx = 0; kx < 7; kx++)
        acc = __fadd_rn(acc, __fmul_rn(wq[ky * 7 + kx], rowv[kx]));
    }
  }
  y2[(size_t)tb * 576 + oc * 9 + p] = __fadd_rn(acc, b2[oc]);
}

// ============ K9: GN2 apply + GLIF2 -> h2 f32 spikes [tb,576] ============
__global__ __launch_bounds__(256) void f_glif2(
    const float* __restrict__ y2, const float2* __restrict__ mr2,
    const float* __restrict__ gnw, const float* __restrict__ gnb, float* __restrict__ h2)
{
  int gid = blockIdx.x * 256 + threadIdx.x;
  if (gid >= 73728) return;
  int b = gid / 576;
  int e = gid % 576;
  int c = e / 9;
  int g = e / 72;
  float gw = gnw[c], gb = gnb[c];
  float ii = 0.f, vv = 0.f, ss = 0.f, aa = 0.f;
  for (int t = 0; t < 8; t++) {
    int tb = t * 128 + b;
    float2 mrv = mr2[tb * 8 + g];
    float xn = gn_apply(y2[(size_t)tb * 576 + e], mrv.x, mrv.y, gw, gb);
    float ns = glif_step(xn, ii, vv, ss, aa);
    h2[(size_t)tb * 576 + e] = ns;
  }
}

// ============ K10: fused MHA (block per tb); per-output chains == r8's 4 separate kernels ============
__global__ __launch_bounds__(256) void f_mha(
    const float* __restrict__ h2, const float* __restrict__ wi, const float* __restrict__ bi,
    const float* __restrict__ wo, const float* __restrict__ bo, float* __restrict__ feat)
{
  int tb = blockIdx.x;
  int tid = threadIdx.x;
  __shared__ float tokl[576];    // [s][64]
  __shared__ float qkvl[1728];   // [s][192]
  __shared__ float attl[324];    // [h][qi][kj]
  __shared__ float obufl[576];   // [s][64]
  for (int i = tid; i < 576; i += 256) {
    int c = i / 9, s = i % 9;
    tokl[s * 64 + c] = h2[(size_t)tb * 576 + i];
  }
  __syncthreads();
  // qkv: fma chain over c ascending, bias after (== f_qkv)
  for (int o = tid; o < 1728; o += 256) {
    int s = o / 192, j = o % 192;
    const float* wr = wi + j * 64;
    const float* tr = tokl + s * 64;
    float acc = 0.0f;
    for (int c = 0; c < 64; c++) acc = __fmaf_rn(tr[c], wr[c], acc);
    qkvl[o] = __fadd_rn(acc, bi[j]);
  }
  __syncthreads();
  // logits (mul+add over d) + softmax (np tree) (== f_att)
  if (tid < 36) {
    int qi = tid % 9;
    int h = tid / 9;
    float lg[9];
    for (int kj = 0; kj < 9; kj++) {
      float acc = 0.0f;
      for (int d = 0; d < 16; d++)
        acc = __fadd_rn(acc, __fmul_rn(qkvl[qi * 192 + h * 16 + d],
                                       qkvl[kj * 192 + 64 + h * 16 + d]));
      lg[kj] = __fmul_rn(acc, 0.25f);
    }
    float mx = lg[0];
    for (int kj = 1; kj < 9; kj++) mx = fmaxf(mx, lg[kj]);
    float ev[9];
    for (int kj = 0; kj < 9; kj++) ev[kj] = np_exp(__fsub_rn(lg[kj], mx));
    float s01 = __fadd_rn(ev[0], ev[1]), s23 = __fadd_rn(ev[2], ev[3]);
    float s45 = __fadd_rn(ev[4], ev[5]), s67 = __fadd_rn(ev[6], ev[7]);
    float sum = __fadd_rn(__fadd_rn(s01, s23), __fadd_rn(s45, s67));
    sum = __fadd_rn(sum, ev[8]);
    for (int kj = 0; kj < 9; kj++)
      attl[h * 81 + qi * 9 + kj] = __fdiv_rn(ev[kj], sum);
  }
  __syncthreads();
  // att @ V: mul+add over j ascending (== f_attv)
  for (int o = tid; o < 576; o += 256) {
    int f = o % 64;
    int s = o / 64;
    int h = f >> 4;
    float acc = 0.0f;
    for (int j = 0; j < 9; j++)
      acc = __fadd_rn(acc, __fmul_rn(attl[h * 81 + s * 9 + j], qkvl[j * 192 + 128 + f]));
    obufl[s * 64 + f] = acc;
  }
  __syncthreads();
  // out-proj: fma chain over f ascending, bias after (== f_proj)
  for (int o = tid; o < 576; o += 256) {
    int s = o % 9;
    int e = o / 9;
    float acc = 0.0f;
    for (int f = 0; f < 64; f++)
      acc = __fmaf_rn(obufl[s * 64 + f], wo[e * 64 + f], acc);
    feat[(size_t)tb * 576 + e * 9 + s] = __fadd_rn(acc, bo[e]);
  }
}

// ============ K11: FC tiled GEMM; chain k=0..575 ascending fma, bias after ============
__global__ __launch_bounds__(256) void f_fc(
    const float* __restrict__ feat, const float* __restrict__ fw, const float* __restrict__ fb,
    float* __restrict__ yfc)
{
  int mb = blockIdx.x;
  int nb = blockIdx.y;
  int tid = threadIdx.x;
  __shared__ float At[32 * 68];
  __shared__ float Bt[32 * 68];
  int tn = tid >> 4, tm = tid & 15;
  int n4 = tn * 4, m4 = tm * 4;
  float acc[4][4];
#pragma unroll
  for (int i = 0; i < 4; i++)
#pragma unroll
    for (int j = 0; j < 4; j++) acc[i][j] = 0.0f;
  for (int kc = 0; kc < 18; kc++) {
    int k0 = kc * 32;
    __syncthreads();
    for (int l = tid; l < 2048; l += 256) {
      int n = l >> 5, k = l & 31;
      At[k * 68 + n] = feat[(size_t)(nb * 64 + n) * 576 + k0 + k];
      Bt[k * 68 + n] = fw[(size_t)(mb * 64 + n) * 576 + k0 + k];
    }
    __syncthreads();
#pragma unroll 8
    for (int k = 0; k < 32; k++) {
      float av[4], bv[4];
#pragma unroll
      for (int i = 0; i < 4; i++) av[i] = At[k * 68 + n4 + i];
#pragma unroll
      for (int j = 0; j < 4; j++) bv[j] = Bt[k * 68 + m4 + j];
#pragma unroll
      for (int i = 0; i < 4; i++)
#pragma unroll
        for (int j = 0; j < 4; j++) acc[i][j] = __fmaf_rn(av[i], bv[j], acc[i][j]);
    }
  }
#pragma unroll
  for (int i = 0; i < 4; i++) {
    int n = nb * 64 + n4 + i;
    int m = mb * 64 + m4;
#pragma unroll
    for (int j = 0; j < 4; j++)
      yfc[(size_t)n * 2304 + m + j] = __fadd_rn(acc[i][j], fb[m + j]);
  }
}

// ============ K13: GNfc apply + GLIFfc -> hf u8 [t][b][2304] ============
__global__ __launch_bounds__(256) void f_gliffc(
    const float* __restrict__ yfc, const float2* __restrict__ mrfc,
    const float* __restrict__ gnw, const float* __restrict__ gnb, unsigned char* __restrict__ hf)
{
  int gid = blockIdx.x * 256 + threadIdx.x;
  if (gid >= 294912) return;
  int c = gid % 2304;
  int b = gid / 2304;
  int g = c / 72;
  float gw = gnw[c], gb = gnb[c];
  float ii = 0.f, vv = 0.f, ss = 0.f, aa = 0.f;
  for (int t = 0; t < 8; t++) {
    int tb = t * 128 + b;
    float2 mrv = mrfc[tb * 32 + g];
    float xn = gn_apply(yfc[(size_t)tb * 2304 + c], mrv.x, mrv.y, gw, gb);
    float ns = glif_step(xn, ii, vv, ss, aa);
    hf[(size_t)t * 294912 + (size_t)b * 2304 + c] = (unsigned char)ns;
  }
}

// ============ K14a: head per (b,nc,t): fma chain c ascending (uint-packed spike loads) ============
__global__ __launch_bounds__(256) void f_head_t(
    const unsigned char* __restrict__ hf, const float* __restrict__ head_w,
    const float* __restrict__ head_b, const float* __restrict__ wt, float* __restrict__ hbuf)
{
  int gid = blockIdx.x * 256 + threadIdx.x;
  if (gid >= 9216) return;
  int t = gid % 8;
  int nc = (gid / 8) % 9;
  int b = gid / 72;
  const float* wr = head_w + (size_t)nc * 2304;
  const unsigned int* hr = (const unsigned int*)(hf + (size_t)t * 294912 + (size_t)b * 2304);
  float acc = 0.0f;
  for (int c4 = 0; c4 < 576; c4++) {
    unsigned int u = hr[c4];
    int c = c4 * 4;
    acc = __fmaf_rn((float)(u & 0xFF), wr[c], acc);
    acc = __fmaf_rn((float)((u >> 8) & 0xFF), wr[c + 1], acc);
    acc = __fmaf_rn((float)((u >> 16) & 0xFF), wr[c + 2], acc);
    acc = __fmaf_rn((float)((u >> 24) & 0xFF), wr[c + 3], acc);
  }
  float ot = __fadd_rn(acc, head_b[nc]);
  hbuf[gid] = __fmul_rn(ot, wt[t]);
}

// ============ K14b: sum over t ascending ============
__global__ __launch_bounds__(256) void f_head_sum(
    const float* __restrict__ hbuf, float* __restrict__ out)
{
  int gid = blockIdx.x * 256 + threadIdx.x;
  if (gid >= 1152) return;
  float outv = 0.0f;
  for (int t = 0; t < 8; t++) outv = __fadd_rn(outv, hbuf[gid * 8 + t]);
  out[gid] = outv;
}

// ===================== launch =====================
extern "C" void kernel_launch(void* const* d_in, const int* in_sizes, int n_in,
                              void* d_out, int out_size, void* d_ws, size_t ws_size,
                              hipStream_t stream) {
  (void)in_sizes; (void)n_in; (void)out_size; (void)ws_size;
  const float* x       = (const float*)d_in[0];
  const float* conv0_w = (const float*)d_in[1];
  const float* conv0_b = (const float*)d_in[2];
  const float* gn0_w   = (const float*)d_in[3];
  const float* gn0_b   = (const float*)d_in[4];
  const float* conv1_w = (const float*)d_in[5];
  const float* conv1_b = (const float*)d_in[6];
  const float* gn1_w   = (const float*)d_in[7];
  const float* gn1_b   = (const float*)d_in[8];
  const float* conv2_w = (const float*)d_in[9];
  const float* conv2_b = (const float*)d_in[10];
  const float* gn2_w   = (const float*)d_in[11];
  const float* gn2_b   = (const float*)d_in[12];
  const float* wi      = (const float*)d_in[13];
  const float* bi      = (const float*)d_in[14];
  const float* wo      = (const float*)d_in[15];
  const float* bo      = (const float*)d_in[16];
  const float* fc_w    = (const float*)d_in[17];
  const float* fc_b    = (const float*)d_in[18];
  const float* gnfc_w  = (const float*)d_in[19];
  const float* gnfc_b  = (const float*)d_in[20];
  const float* head_w  = (const float*)d_in[21];
  const float* head_b  = (const float*)d_in[22];
  const float* w_t     = (const float*)d_in[23];

  // workspace layout: identical to the r8 PASSING build
  char* ws = (char*)d_ws;
  unsigned char* h0   = (unsigned char*)(ws);               // [0, 58982400)
  float*         c0   = (float*)(ws + 58982400);            // 29491200 B -> 88473600
  float*         y1   = (float*)(ws + 88473600);            // 37748736 B -> 126222336
  unsigned char* h1   = (unsigned char*)(ws + 126222336);   //  9437184 B -> 135659520
  float*         y2   = (float*)(ws + 135659520);           //  2359296 B -> 138018816
  float*         h2   = (float*)(ws + 138018816);           //  2359296 B -> 140378112
  // late-phase buffers alias c0's region (c0 dead after f_glif0)
  float*         feat = (float*)(ws + 69746688);            //  2359296 B -> 72105984
  float*         yfc  = (float*)(ws + 72105984);            //  9437184 B -> 81543168
  unsigned char* hf   = (unsigned char*)(ws + 81543168);    //  2359296 B -> 83902464 (< 88473600 OK)
  float2*        mr0  = (float2*)(ws + 151142400);          //     8192 B
  float2*        mr1  = (float2*)(ws + 151150592);          //    65536 B
  float2*        mr2  = (float2*)(ws + 151216128);          //    65536 B
  float2*        mrfc = (float2*)(ws + 151281664);          //   262144 B -> 151543808
  float*         hbuf = (float*)(ws + 151543808);           //    36864 B -> 151580672

  f_conv0<<<28800, 256, 0, stream>>>(x, conv0_w, conv0_b, c0);
  f_stats_wave<<<1024, 64, 0, stream>>>(c0, mr0, 7200);
  f_glif0<<<28800, 256, 0, stream>>>(c0, mr0, gn0_w, gn0_b, h0);
  f_conv1<<<1024, 256, 0, stream>>>(h0, conv1_w, conv1_b, y1);
  f_stats_wave<<<8192, 64, 0, stream>>>(y1, mr1, 1152);
  f_glif1<<<4608, 256, 0, stream>>>(y1, mr1, gn1_w, gn1_b, h1);
  f_conv2<<<1024, 576, 0, stream>>>(h1, conv2_w, conv2_b, y2);
  f_stats_serial<<<32, 256, 0, stream>>>(y2, mr2, 8192);
  f_glif2<<<288, 256, 0, stream>>>(y2, mr2, gn2_w, gn2_b, h2);
  f_mha<<<1024, 256, 0, stream>>>(h2, wi, bi, wo, bo, feat);
  dim3 gfc(36, 16);
  f_fc<<<gfc, 256, 0, stream>>>(feat, fc_w, fc_b, yfc);
  f_stats_serial<<<128, 256, 0, stream>>>(yfc, mrfc, 32768);
  f_gliffc<<<1152, 256, 0, stream>>>(yfc, mrfc, gnfc_w, gnfc_b, hf);
  f_head_t<<<36, 256, 0, stream>>>(hf, head_w, head_b, w_t, hbuf);
  f_head_sum<<<5, 256, 0, stream>>>(hbuf, (float*)d_out);
}